// Round 4
// baseline (9417.549 us; speedup 1.0000x reference)
//
#include <hip/hip_runtime.h>
#include <stdint.h>

// DBN downbeat Viterbi, single persistent 1024-thread workgroup, v in REGISTERS.
// Thread tid owns states [tid*16, tid*16+16); S <= 16384. Per frame:
//   phase A: 240-way argmax over lastv (block-last values, LDS) + dens compute
//   phase B: register shift (v_new[s] = v_old[s-1] + dens[ptr]) + head fixups
// 2 barriers/frame, ~4KB static LDS. OUTPUT: float32 (path states + logp).
// Backpointers: u8 argmax per (beat,tempo) per frame in ws; backtrace skips runs.

#define NB 4
#define KF 16
#define QW 16
#define NPMAX 256
#define NEGV -1.0e30f

__device__ __forceinline__ float bf16u_to_f(uint16_t u) {
    union { uint32_t i; float f; } v; v.i = ((uint32_t)u) << 16; return v.f;
}

__global__ __launch_bounds__(1024) void dbn_viterbi_kernel(
    const void* __restrict__ acts_raw,     // F*2, f32 or bf16 (detected)
    const void* __restrict__ lt_raw,       // NB*T*T, f32 or bf16
    const int*  __restrict__ prev_last,    // NB*T
    const int*  __restrict__ first_states, // NB*T
    const int*  __restrict__ pointer,      // S
    float*      __restrict__ out,          // F+1 float32 values
    uint8_t*    __restrict__ ws_argi,      // F*NP argmax indices
    int T, int S, int F)
{
    const int tid  = (int)threadIdx.x;
    const int NP   = NB * T;
    const int lane = tid & 63;
    const int wvx  = tid >> 6;

    __shared__ alignas(16) float lastv[NB * 64];   // [beat][tempo], pad = NEGV
    __shared__ float bestv[NPMAX];
    __shared__ float bound[16];        // per-wave lane63 vreg[KF-1]
    __shared__ int   fsld[NPMAX];
    __shared__ int   plds[NPMAX];
    __shared__ float dens_s[4];
    __shared__ float wvs[16];
    __shared__ int   wss[16];
    __shared__ int   flag_s;

    // ---- dtype detection on acts (bf16 exponent bytes in [0x20,0x40))
    if (tid == 0) {
        const uint16_t* au = (const uint16_t*)acts_raw;
        int bf = 1;
        for (int i = 0; i < 32; i++) {
            uint16_t e = au[2 * i];
            uint8_t hb = (uint8_t)(e >> 8);
            if (!(e == 0 || (hb >= 0x20 && hb < 0x40))) bf = 0;
        }
        flag_s = bf;
    }
    if (tid < NP)      { fsld[tid] = first_states[tid]; plds[tid] = prev_last[tid]; }
    if (tid < NB * 64) lastv[tid] = NEGV;
    __syncthreads();
    const int isbf = flag_s;
    const uint16_t* lt_u = (const uint16_t*)lt_raw;
    const float*    lt_f = (const float*)lt_raw;
    const uint16_t* ac_u = (const uint16_t*)acts_raw;
    const float*    ac_f = (const float*)acts_raw;

    // ---- argmax-side setup: transition column in registers
    const int g = tid >> 2, k = tid & 3;
    const bool act_g = (g < NP);
    float ltreg[QW];
    #pragma unroll
    for (int u = 0; u < QW; u++) ltreg[u] = NEGV;
    int rowbase = 0;
    if (act_g) {
        int b = g / T, j = g - (g / T) * T;
        rowbase = ((b + 3) & 3) << 6;                // prev beat row
        #pragma unroll
        for (int u = 0; u < QW; u++) {
            int i = k * QW + u;
            if (i < T) {
                int idx = (b * T + i) * T + j;
                ltreg[u] = isbf ? bf16u_to_f(lt_u[idx]) : lt_f[idx];
            }
        }
    }

    // ---- update-side setup: per-state metadata (contiguous ownership)
    const int nsb  = S / NB;
    const int base = tid * KF;
    uint32_t hmask = 0;      // bit kk: pointer[s] != 0
    uint32_t pv = 0;         // the (unique) nonzero pointer value among owned states
    int fkk = -1, lkk = -1, fq = 0, lq = 0;
    #pragma unroll
    for (int kk = 0; kk < KF; kk++) {
        int s = base + kk;
        if (s < S) {
            int b2 = s / nsb;
            int lo = b2 * T, hi = lo + T - 1;
            while (lo < hi) { int mid = (lo + hi + 1) >> 1; if (fsld[mid] <= s) lo = mid; else hi = mid - 1; }
            int p  = lo;
            int ib = p - b2 * T;
            int end = (ib + 1 < T) ? fsld[p + 1] : (b2 + 1) * nsb;
            int pt = pointer[s] & 3;
            if (pt) { hmask |= (1u << kk); pv = (uint32_t)pt; }
            if (s == fsld[p]) { fkk = kk; fq = p; }
            if (s == end - 1) { lkk = kk; lq = (b2 << 6) + ib; }
        }
    }

    // ---- init v and publish initial lastv/bound
    const float vinit = -logf((float)S);
    float vreg[KF];
    #pragma unroll
    for (int kk = 0; kk < KF; kk++) vreg[kk] = vinit;
    if (lkk >= 0)   lastv[lq]  = vinit;
    if (lane == 63) bound[wvx] = vinit;

    // ---- main loop, 2 barriers/frame
    for (int t = 0; t < F; t++) {
        __syncthreads();   // A: lastv/bound of frame t-1 visible

        // dens by tail threads (inactive in argmax); exact reference formulas
        if (tid >= 1020 && tid < 1023) {
            int c3 = tid - 1020;
            float ab, ad;
            if (isbf) { ab = bf16u_to_f(ac_u[2 * t]); ad = bf16u_to_f(ac_u[2 * t + 1]); }
            else      { ab = ac_f[2 * t];             ad = ac_f[2 * t + 1]; }
            dens_s[c3] = (c3 == 0) ? logf(((1.0f - ab) - ad) / 15.0f)
                       : (c3 == 1) ? logf(ab) : logf(ad);
        }

        // argmax over from-tempi (4 lanes per (beat,tempo)), first-max tie-break
        if (act_g) {
            const float* rowp = &lastv[rowbase + k * QW];
            float4 l0 = *(const float4*)(rowp + 0);
            float4 l1 = *(const float4*)(rowp + 4);
            float4 l2 = *(const float4*)(rowp + 8);
            float4 l3 = *(const float4*)(rowp + 12);
            float cand[QW] = { l0.x, l0.y, l0.z, l0.w, l1.x, l1.y, l1.z, l1.w,
                               l2.x, l2.y, l2.z, l2.w, l3.x, l3.y, l3.z, l3.w };
            float mv = -INFINITY; int ai = 0;
            #pragma unroll
            for (int u = 0; u < QW; u++) {
                float sc = cand[u] + ltreg[u];
                if (sc > mv) { mv = sc; ai = k * QW + u; }
            }
            #pragma unroll
            for (int d = 1; d <= 2; d <<= 1) {
                float ov = __shfl_xor(mv, d, 64);
                int   oa = __shfl_xor(ai, d, 64);
                if (ov > mv || (ov == mv && oa < ai)) { mv = ov; ai = oa; }
            }
            if (k == 0) {
                bestv[g] = mv;
                ws_argi[(size_t)t * NP + g] = (uint8_t)ai;
            }
        }

        // incoming shifted value for kk==0 (previous thread's top state)
        float vtop = vreg[KF - 1];
        float inc  = __shfl_up(vtop, 1, 64);
        if (lane == 0) inc = bound[(wvx + 15) & 15];

        __syncthreads();   // B: bestv + dens ready; lastv reads done

        float d0 = dens_s[0], d1 = dens_s[1], d2 = dens_s[2];
        float dpv  = (pv == 1u) ? d1 : ((pv == 2u) ? d2 : d0);
        float bfix = (fkk >= 0) ? (bestv[fq] + dpv) : 0.0f;  // head: pt != 0 always
        float lval = 0.0f;
        #pragma unroll
        for (int kk = KF - 1; kk >= 0; kk--) {
            float prev = (kk == 0) ? inc : vreg[kk - 1];
            float add  = ((hmask >> kk) & 1u) ? dpv : d0;
            float val  = prev + add;                 // bit-exact vs reference
            if (kk == fkk) val = bfix;
            vreg[kk] = val;
            if (kk == lkk) lval = val;
        }
        if (lkk >= 0)   lastv[lq]  = lval;
        if (lane == 63) bound[wvx] = vreg[KF - 1];
    }

    // ---- final argmax (first occurrence = smallest s)
    float mv = -INFINITY; int ms = 0x7FFFFFFF;
    #pragma unroll
    for (int kk = 0; kk < KF; kk++) {
        int s = base + kk;
        if (s < S) {
            float v = vreg[kk];
            if (v > mv) { mv = v; ms = s; }
        }
    }
    #pragma unroll
    for (int d = 1; d < 64; d <<= 1) {
        float ov = __shfl_xor(mv, d, 64);
        int   os = __shfl_xor(ms, d, 64);
        if (ov > mv || (ov == mv && os < ms)) { mv = ov; ms = os; }
    }
    if (lane == 0) { wvs[wvx] = mv; wss[wvx] = ms; }
    __syncthreads();

    if (tid == 0) {
        float bm = -INFINITY; int bs = 0x7FFFFFFF;
        for (int w = 0; w < 16; w++) {
            if (wvs[w] > bm || (wvs[w] == bm && wss[w] < bs)) { bm = wvs[w]; bs = wss[w]; }
        }
        // backtrace (f32 output)
        int s = bs;
        int t = F - 1;
        out[F - 1] = (float)s;
        while (t > 0) {
            int b = s / nsb;
            int lo = b * T, hi = lo + T - 1;
            while (lo < hi) { int mid = (lo + hi + 1) >> 1; if (fsld[mid] <= s) lo = mid; else hi = mid - 1; }
            int p = lo;
            int run = s - fsld[p];
            if (run == 0) {
                int ai = ws_argi[(size_t)t * NP + p];
                s = plds[b * T + ai];
                out[t - 1] = (float)s;
                t--;
            } else {
                int m = (run < t) ? run : t;
                for (int j = 0; j < m; j++) out[t - 1 - j] = (float)(s - 1 - j);
                s -= m; t -= m;
            }
        }
        out[F] = bm;   // logp
    }
}

extern "C" void kernel_launch(void* const* d_in, const int* in_sizes, int n_in,
                              void* d_out, int out_size, void* d_ws, size_t ws_size,
                              hipStream_t stream) {
    const int F  = in_sizes[0] / 2;     // frames
    const int NP = in_sizes[2];         // NB*T
    const int T  = NP / NB;             // tempi
    const int S  = in_sizes[4];         // total states

    hipLaunchKernelGGL(dbn_viterbi_kernel, dim3(1), dim3(1024), 0, stream,
                       d_in[0], d_in[1],
                       (const int*)d_in[2], (const int*)d_in[3], (const int*)d_in[4],
                       (float*)d_out, (uint8_t*)d_ws,
                       T, S, F);
}

// Round 6
// 8625.559 us; speedup vs baseline: 1.0918x; 1.0918x over previous
//
#include <hip/hip_runtime.h>
#include <stdint.h>

// DBN downbeat Viterbi, single persistent 1024-thread workgroup, v in REGISTERS.
// Thread tid owns states [tid*15, tid*15+15); S <= 15360. Per frame:
//   phase A: 240-way argmax over lastv (LDS, aligned float4 broadcast reads),
//            DPP quad_perm reduce; dens by 3 spare wave-15 lanes (acts prefetched)
//   phase B: register shift update, DESCENDING kk (in-place safe!)
// 2 barriers/frame. ws_argi staged in LDS ring, flushed every 32 frames.
// Output: float32 (path + logp). Backtrace skips within-block runs.

#define NB 4
#define KF 15
#define QW 16
#define NPMAX 256
#define TBATCH 32
#define NEGV -1.0e30f

__device__ __forceinline__ float bf16u_to_f(uint16_t u) {
    union { uint32_t i; float f; } v; v.i = ((uint32_t)u) << 16; return v.f;
}

template<int CTRL>
__device__ __forceinline__ int dpp_i(int x) {
    return __builtin_amdgcn_update_dpp(0, x, CTRL, 0xF, 0xF, true);
}
template<int CTRL>
__device__ __forceinline__ float dpp_f(float x) {
    return __int_as_float(dpp_i<CTRL>(__float_as_int(x)));
}

__device__ __forceinline__ void load_acts(const void* p, int isbf, int t, float& a, float& d) {
    if (isbf) {
        const uint16_t* u = (const uint16_t*)p;
        uint32_t w = *(const uint32_t*)(u + 2 * t);
        a = bf16u_to_f((uint16_t)w); d = bf16u_to_f((uint16_t)(w >> 16));
    } else {
        const float2* f = (const float2*)p;
        float2 v = f[t]; a = v.x; d = v.y;
    }
}

__global__ __launch_bounds__(1024) void dbn_viterbi_kernel(
    const void* __restrict__ acts_raw,     // F*2, f32 or bf16 (detected)
    const void* __restrict__ lt_raw,       // NB*T*T, f32 or bf16
    const int*  __restrict__ prev_last,    // NB*T
    const int*  __restrict__ first_states, // NB*T
    const int*  __restrict__ pointer,      // S
    float*      __restrict__ out,          // F+1 float32 values
    uint8_t*    __restrict__ ws_argi,      // F*NP argmax indices
    int T, int S, int F)
{
    const int tid  = (int)threadIdx.x;
    const int NP   = NB * T;
    const int lane = tid & 63;
    const int wvx  = tid >> 6;

    __shared__ alignas(16) float lastv[NB * 64];   // [beat][tempo], pad = NEGV
    __shared__ float bestv[NPMAX];
    __shared__ float bound[16];
    __shared__ int   fsld[NPMAX];
    __shared__ int   plds[NPMAX];
    __shared__ float dens_s[4];
    __shared__ float wvs[16];
    __shared__ int   wss[16];
    __shared__ int   flag_s;
    __shared__ uint8_t argi_s[TBATCH * 240 + 16];  // 32-frame ring

    // ---- dtype detection on acts (bf16 exponent bytes in [0x20,0x40))
    if (tid == 0) {
        const uint16_t* au = (const uint16_t*)acts_raw;
        int bf = 1;
        for (int i = 0; i < 32; i++) {
            uint16_t e = au[2 * i];
            uint8_t hb = (uint8_t)(e >> 8);
            if (!(e == 0 || (hb >= 0x20 && hb < 0x40))) bf = 0;
        }
        flag_s = bf;
    }
    if (tid < NP)      { fsld[tid] = first_states[tid]; plds[tid] = prev_last[tid]; }
    if (tid < NB * 64) lastv[tid] = NEGV;
    __syncthreads();
    const int isbf = flag_s;
    const uint16_t* lt_u = (const uint16_t*)lt_raw;
    const float*    lt_f = (const float*)lt_raw;

    // ---- argmax-side setup: transition column in registers (aligned 16-chunks)
    const int g = tid >> 2, k = tid & 3;
    const bool act_g = (g < NP);
    float ltreg[QW];
    #pragma unroll
    for (int u = 0; u < QW; u++) ltreg[u] = NEGV;
    int rowbase = 0;
    if (act_g) {
        int b = g / T, j = g - (g / T) * T;
        rowbase = ((b + 3) & 3) << 6;                // prev-beat row
        #pragma unroll
        for (int u = 0; u < QW; u++) {
            int i = k * QW + u;
            if (i < T) {
                int idx = (b * T + i) * T + j;
                ltreg[u] = isbf ? bf16u_to_f(lt_u[idx]) : lt_f[idx];
            }
        }
    }

    // ---- update-side setup: per-state metadata (uniform 15 states/thread)
    const int nsb  = S / NB;
    const int base = tid * KF;
    bool hb[KF], isf[KF], isl[KF];
    uint32_t pv = 0;
    int fq = 0, lq = 0;
    bool has_l = false;
    #pragma unroll
    for (int kk = 0; kk < KF; kk++) {
        int s = base + kk;
        bool vh = false, vf = false, vl = false;
        if (s < S) {
            int b2 = s / nsb;
            int lo = b2 * T, hi = lo + T - 1;
            while (lo < hi) { int mid = (lo + hi + 1) >> 1; if (fsld[mid] <= s) lo = mid; else hi = mid - 1; }
            int p  = lo;
            int ib = p - b2 * T;
            int end = (ib + 1 < T) ? fsld[p + 1] : (b2 + 1) * nsb;
            int pt = pointer[s] & 3;
            if (pt) { vh = true; pv = (uint32_t)pt; }
            if (s == fsld[p]) { vf = true; fq = p; }
            if (s == end - 1) { vl = true; lq = (b2 << 6) + ib; has_l = true; }
        }
        hb[kk] = vh; isf[kk] = vf; isl[kk] = vl;
    }

    // ---- init v, lastv, bound; prefetch acts(0)
    const float vinit = -logf((float)S);
    float vreg[KF];
    #pragma unroll
    for (int kk = 0; kk < KF; kk++) vreg[kk] = vinit;
    if (has_l)      lastv[lq]  = vinit;
    if (lane == 63) bound[wvx] = vinit;
    float inc_pipe = vinit;
    float ab_c = 0.0f, ad_c = 0.0f;
    if (wvx == 15 && lane >= 60 && lane < 63) load_acts(acts_raw, isbf, 0, ab_c, ad_c);

    // ---- main loop, 2 barriers/frame
    for (int t = 0; t < F; t++) {
        const int tB = t & (TBATCH - 1);
        __syncthreads();   // A: lastv/bound of frame t-1 visible

        float inc_use = inc_pipe;
        if (lane == 0) inc_use = bound[(wvx + 15) & 15];

        if (wvx == 15) {
            // dens from prefetched acts; then prefetch next frame
            if (lane >= 60 && lane < 63) {
                int c3 = lane - 60;
                float dv = (c3 == 0) ? logf(((1.0f - ab_c) - ad_c) / 15.0f)
                         : (c3 == 1) ? logf(ab_c) : logf(ad_c);
                dens_s[c3] = dv;
                if (t + 1 < F) load_acts(acts_raw, isbf, t + 1, ab_c, ad_c);
            }
        } else if (act_g) {
            // argmax over from-tempi (4 lanes per (beat,tempo)), first-max tie-break
            const float* rowp = &lastv[rowbase + k * QW];
            float4 l0 = *(const float4*)(rowp + 0);
            float4 l1 = *(const float4*)(rowp + 4);
            float4 l2 = *(const float4*)(rowp + 8);
            float4 l3 = *(const float4*)(rowp + 12);
            float cand[QW] = { l0.x, l0.y, l0.z, l0.w, l1.x, l1.y, l1.z, l1.w,
                               l2.x, l2.y, l2.z, l2.w, l3.x, l3.y, l3.z, l3.w };
            float mv = -INFINITY; int ai = 0;
            #pragma unroll
            for (int u = 0; u < QW; u++) {
                float sc = cand[u] + ltreg[u];
                if (sc > mv) { mv = sc; ai = k * QW + u; }
            }
            {   // quad reduce via DPP
                float ov = dpp_f<0xB1>(mv); int oa = dpp_i<0xB1>(ai);
                if (ov > mv || (ov == mv && oa < ai)) { mv = ov; ai = oa; }
                ov = dpp_f<0x4E>(mv); oa = dpp_i<0x4E>(ai);
                if (ov > mv || (ov == mv && oa < ai)) { mv = ov; ai = oa; }
            }
            if (k == 0) {
                bestv[g] = mv;
                argi_s[tB * NP + g] = (uint8_t)ai;
            }
        }

        __syncthreads();   // B: bestv + dens visible; lastv reads done

        float d0 = dens_s[0], d1 = dens_s[1], d2 = dens_s[2];
        float dpv = (pv == 1u) ? d1 : ((pv == 2u) ? d2 : d0);
        float bq  = bestv[fq];
        float lval = 0.0f;
        // DESCENDING kk: vreg[kk-1] must still hold the OLD value when read.
        #pragma unroll
        for (int kk = KF - 1; kk >= 0; kk--) {
            float prev = (kk == 0) ? inc_use : vreg[kk - 1];
            prev = isf[kk] ? bq  : prev;
            float add = hb[kk] ? dpv : d0;
            float val = prev + add;               // bit-exact vs reference
            vreg[kk] = val;
            lval = isl[kk] ? val : lval;
        }
        if (has_l)      lastv[lq]  = lval;
        if (lane == 63) bound[wvx] = vreg[KF - 1];
        inc_pipe = __shfl_up(vreg[KF - 1], 1, 64);

        // flush argi ring every TBATCH frames (and at the end)
        if (tB == TBATCH - 1 || t == F - 1) {
            int nbytes = (tB + 1) * NP;           // multiple of 4 (NP % 4 == 0)
            int t0 = t - tB;
            for (int off = tid * 4; off < nbytes; off += 4096) {
                uint32_t w = *(const uint32_t*)&argi_s[off];
                *(uint32_t*)&ws_argi[(size_t)t0 * NP + off] = w;
            }
        }
    }

    // ---- final argmax (first occurrence = smallest s)
    __syncthreads();
    float mv = -INFINITY; int ms = 0x7FFFFFFF;
    #pragma unroll
    for (int kk = 0; kk < KF; kk++) {
        int s = base + kk;
        if (s < S) {
            float v = vreg[kk];
            if (v > mv) { mv = v; ms = s; }
        }
    }
    #pragma unroll
    for (int d = 1; d < 64; d <<= 1) {
        float ov = __shfl_xor(mv, d, 64);
        int   os = __shfl_xor(ms, d, 64);
        if (ov > mv || (ov == mv && os < ms)) { mv = ov; ms = os; }
    }
    if (lane == 0) { wvs[wvx] = mv; wss[wvx] = ms; }
    __syncthreads();

    if (tid == 0) {
        float bm = -INFINITY; int bs = 0x7FFFFFFF;
        for (int w = 0; w < 16; w++) {
            if (wvs[w] > bm || (wvs[w] == bm && wss[w] < bs)) { bm = wvs[w]; bs = wss[w]; }
        }
        // backtrace (f32 output)
        int s = bs;
        int t = F - 1;
        out[F - 1] = (float)s;
        while (t > 0) {
            int b = s / nsb;
            int lo = b * T, hi = lo + T - 1;
            while (lo < hi) { int mid = (lo + hi + 1) >> 1; if (fsld[mid] <= s) lo = mid; else hi = mid - 1; }
            int p = lo;
            int run = s - fsld[p];
            if (run == 0) {
                int ai = ws_argi[(size_t)t * NP + p];
                s = plds[b * T + ai];
                out[t - 1] = (float)s;
                t--;
            } else {
                int m = (run < t) ? run : t;
                for (int j = 0; j < m; j++) out[t - 1 - j] = (float)(s - 1 - j);
                s -= m; t -= m;
            }
        }
        out[F] = bm;   // logp
    }
}

extern "C" void kernel_launch(void* const* d_in, const int* in_sizes, int n_in,
                              void* d_out, int out_size, void* d_ws, size_t ws_size,
                              hipStream_t stream) {
    const int F  = in_sizes[0] / 2;     // frames
    const int NP = in_sizes[2];         // NB*T
    const int T  = NP / NB;             // tempi
    const int S  = in_sizes[4];         // total states

    hipLaunchKernelGGL(dbn_viterbi_kernel, dim3(1), dim3(1024), 0, stream,
                       d_in[0], d_in[1],
                       (const int*)d_in[2], (const int*)d_in[3], (const int*)d_in[4],
                       (float*)d_out, (uint8_t*)d_ws,
                       T, S, F);
}

// Round 7
// 6490.342 us; speedup vs baseline: 1.4510x; 1.3290x over previous
//
#include <hip/hip_runtime.h>
#include <stdint.h>

// DBN downbeat Viterbi, single persistent 1024-thread workgroup, v in REGISTERS.
// End-aligned block ownership: block g (length L) gets n=ceil(L/15) threads;
// its last thread owns the final 15 states -> lastv = vreg[14] (static).
// First thread has lead-in dead slots; head/dead handled by hq mask (prev->bq).
// Phase A: 240-group max-only argmax over lastv (double-buffered LDS);
// Phase B: register shift update (descending kk, 3 VALU/state).
// FAST path: wave 15 streams lastv(t-1) to ws (float4) during phase B;
// backtrace recomputes argmax indices exactly in reference scan order.
// FALLBACK (small ws / T%4!=0): round-6 index-tracking argmax + u8 argi ring.
// Output: float32 (path + logp). Bit-exact vs reference.

#define NB 4
#define KF 15
#define QW 16
#define NPMAX 256
#define TBATCH 32
#define NEGV -1.0e30f

__device__ __forceinline__ float bf16u_to_f(uint16_t u) {
    union { uint32_t i; float f; } v; v.i = ((uint32_t)u) << 16; return v.f;
}

template<int CTRL>
__device__ __forceinline__ int dpp_i(int x) {
    return __builtin_amdgcn_update_dpp(0, x, CTRL, 0xF, 0xF, true);
}
template<int CTRL>
__device__ __forceinline__ float dpp_f(float x) {
    return __int_as_float(dpp_i<CTRL>(__float_as_int(x)));
}

__device__ __forceinline__ void load_acts(const void* p, int isbf, int t, float& a, float& d) {
    if (isbf) {
        const uint16_t* u = (const uint16_t*)p;
        uint32_t w = *(const uint32_t*)(u + 2 * t);
        a = bf16u_to_f((uint16_t)w); d = bf16u_to_f((uint16_t)(w >> 16));
    } else {
        const float2* f = (const float2*)p;
        float2 v = f[t]; a = v.x; d = v.y;
    }
}

template<bool FAST>
__global__ __launch_bounds__(1024) void dbn_viterbi_kernel(
    const void* __restrict__ acts_raw,     // F*2, f32 or bf16 (detected)
    const void* __restrict__ lt_raw,       // NB*T*T, f32 or bf16
    const int*  __restrict__ prev_last,    // NB*T
    const int*  __restrict__ first_states, // NB*T
    float*      __restrict__ out,          // F+1 float32
    float*      __restrict__ ws_lastv,     // FAST: F*NP floats
    uint8_t*    __restrict__ ws_argi,      // FALLBACK: F*NP bytes
    int T, int S, int F)
{
    const int tid  = (int)threadIdx.x;
    const int NP   = NB * T;
    const int lane = tid & 63;
    const int wvx  = tid >> 6;

    __shared__ alignas(16) float lastv2[2 * NB * 64];  // double-buffered [2][beat][64]
    __shared__ float bestv[NPMAX];
    __shared__ float bound[16];
    __shared__ int   fsld[NPMAX];
    __shared__ int   plds[NPMAX];
    __shared__ int   pref[NPMAX + 1];
    __shared__ float dens_s[4];
    __shared__ float wvs[16];
    __shared__ int   wss[16];
    __shared__ int   flag_s;
    __shared__ uint8_t argi_s[TBATCH * 240 + 16];      // fallback ring

    // ---- dtype detection on acts
    if (tid == 0) {
        const uint16_t* au = (const uint16_t*)acts_raw;
        int bf = 1;
        for (int i = 0; i < 32; i++) {
            uint16_t e = au[2 * i];
            uint8_t h8 = (uint8_t)(e >> 8);
            if (!(e == 0 || (h8 >= 0x20 && h8 < 0x40))) bf = 0;
        }
        flag_s = bf;
    }
    if (tid < NP)          { fsld[tid] = first_states[tid]; plds[tid] = prev_last[tid]; }
    if (tid < 2 * NB * 64) lastv2[tid] = NEGV;
    __syncthreads();
    const int isbf = flag_s;
    const int nsb  = S / NB;
    const uint16_t* lt_u = (const uint16_t*)lt_raw;
    const float*    lt_f = (const float*)lt_raw;

    // ---- thread-count prefix over blocks (scalar, once)
    if (tid == 0) {
        int acc = 0;
        for (int g = 0; g < NP; g++) {
            int b = g / T, ib = g - b * T;
            int end = (ib + 1 < T) ? fsld[g + 1] : (b + 1) * nsb;
            int L = end - fsld[g];
            pref[g] = acc; acc += (L + KF - 1) / KF;
        }
        pref[NP] = acc;
    }
    __syncthreads();
    const int NT = pref[NP];

    // ---- update-side assignment (end-aligned within block)
    const bool act_u = (tid < NT);
    int g_own = 0, startg = 0, Lg = 1, sb = 0, lq = 0;
    bool is_last = false, pv2 = false;
    if (act_u) {
        int lo = 0, hi = NP - 1;
        while (lo < hi) { int mid = (lo + hi + 1) >> 1; if (pref[mid] <= tid) lo = mid; else hi = mid - 1; }
        g_own = lo;
        int j = tid - pref[lo];
        int b = g_own / T, ib = g_own - b * T;
        startg = fsld[g_own];
        int end = (ib + 1 < T) ? fsld[g_own + 1] : (b + 1) * nsb;
        Lg = end - startg;
        int n = (Lg + KF - 1) / KF;
        sb = startg + Lg - KF * (n - j);
        is_last = (j == n - 1);
        lq = (b << 6) + ib;
        pv2 = (b == 0);
    }
    bool hb[KF], hq[KF];
    #pragma unroll
    for (int kk = 0; kk < KF; kk++) {
        int i = sb + kk - startg;
        hq[kk] = act_u && (i <= 0);            // dead lead-in or head: prev := bq
        hb[kk] = act_u && (16 * i < Lg);       // head-run: addend := dpv (exact vs frac<1/16)
    }

    // ---- argmax-side setup: transition column in registers
    const int g_a = tid >> 2, k4 = tid & 3;
    const bool act_g = (g_a < NP);
    float ltreg[QW];
    #pragma unroll
    for (int u = 0; u < QW; u++) ltreg[u] = NEGV;
    int rowbase = 0;
    if (act_g) {
        int b = g_a / T, j = g_a - (g_a / T) * T;
        rowbase = ((b + 3) & 3) << 6;          // prev-beat row
        #pragma unroll
        for (int u = 0; u < QW; u++) {
            int i = k4 * QW + u;
            if (i < T) {
                int idx = (b * T + i) * T + j;
                ltreg[u] = isbf ? bf16u_to_f(lt_u[idx]) : lt_f[idx];
            }
        }
    }

    // ---- init
    const float vinit = -logf((float)S);
    float vreg[KF];
    #pragma unroll
    for (int kk = 0; kk < KF; kk++) vreg[kk] = vinit;
    if (act_u && is_last) lastv2[256 + lq] = vinit;   // frame 0 reads buffer 1
    if (lane == 63) bound[wvx] = vinit;
    float inc_pipe = vinit;
    float ab_c = 0.0f, ad_c = 0.0f;
    if (wvx == 15 && lane >= 60 && lane < 63) load_acts(acts_raw, isbf, 0, ab_c, ad_c);

    // ---- main loop, 2 barriers/frame
    for (int t = 0; t < F; t++) {
        __syncthreads();   // A: lastv(t-1)/bound visible
        const float* lvR = lastv2 + (((t & 1) ^ 1) << 8);
        float inc_use = inc_pipe;
        if (lane == 0) inc_use = bound[(wvx + 15) & 15];

        if (wvx == 15) {
            if (lane >= 60 && lane < 63) {
                int c3 = lane - 60;
                float dv = (c3 == 0) ? logf(((1.0f - ab_c) - ad_c) / 15.0f)
                         : (c3 == 1) ? logf(ab_c) : logf(ad_c);
                dens_s[c3] = dv;
                if (t + 1 < F) load_acts(acts_raw, isbf, t + 1, ab_c, ad_c);
            }
        } else if (act_g) {
            const float* rowp = &lvR[rowbase + k4 * QW];
            float4 l0 = *(const float4*)(rowp + 0);
            float4 l1 = *(const float4*)(rowp + 4);
            float4 l2 = *(const float4*)(rowp + 8);
            float4 l3 = *(const float4*)(rowp + 12);
            if (FAST) {
                // max-only (index recovered at backtrace)
                float m0 = fmaxf(fmaxf(l0.x + ltreg[0],  l0.y + ltreg[1]),
                                 fmaxf(l0.z + ltreg[2],  l0.w + ltreg[3]));
                float m1 = fmaxf(fmaxf(l1.x + ltreg[4],  l1.y + ltreg[5]),
                                 fmaxf(l1.z + ltreg[6],  l1.w + ltreg[7]));
                float m2 = fmaxf(fmaxf(l2.x + ltreg[8],  l2.y + ltreg[9]),
                                 fmaxf(l2.z + ltreg[10], l2.w + ltreg[11]));
                float m3 = fmaxf(fmaxf(l3.x + ltreg[12], l3.y + ltreg[13]),
                                 fmaxf(l3.z + ltreg[14], l3.w + ltreg[15]));
                float mv = fmaxf(fmaxf(m0, m1), fmaxf(m2, m3));
                mv = fmaxf(mv, dpp_f<0xB1>(mv));
                mv = fmaxf(mv, dpp_f<0x4E>(mv));
                if (k4 == 0) bestv[g_a] = mv;
            } else {
                float cand[QW] = { l0.x, l0.y, l0.z, l0.w, l1.x, l1.y, l1.z, l1.w,
                                   l2.x, l2.y, l2.z, l2.w, l3.x, l3.y, l3.z, l3.w };
                float mv = -INFINITY; int ai = 0;
                #pragma unroll
                for (int u = 0; u < QW; u++) {
                    float sc = cand[u] + ltreg[u];
                    if (sc > mv) { mv = sc; ai = k4 * QW + u; }
                }
                float ov = dpp_f<0xB1>(mv); int oa = dpp_i<0xB1>(ai);
                if (ov > mv || (ov == mv && oa < ai)) { mv = ov; ai = oa; }
                ov = dpp_f<0x4E>(mv); oa = dpp_i<0x4E>(ai);
                if (ov > mv || (ov == mv && oa < ai)) { mv = ov; ai = oa; }
                if (k4 == 0) {
                    bestv[g_a] = mv;
                    argi_s[(t & (TBATCH - 1)) * NP + g_a] = (uint8_t)ai;
                }
            }
        }

        __syncthreads();   // B: bestv + dens visible; lvR reads done
        float d0  = dens_s[0];
        float dpv = pv2 ? dens_s[2] : dens_s[1];
        float bq  = bestv[g_own];
        #pragma unroll
        for (int kk = KF - 1; kk >= 0; kk--) {
            float prev = (kk == 0) ? inc_use : vreg[kk - 1];
            prev = hq[kk] ? bq : prev;
            float add = hb[kk] ? dpv : d0;
            vreg[kk] = prev + add;               // bit-exact vs reference
        }
        float* lvW = lastv2 + ((t & 1) << 8);
        if (act_u && is_last) lvW[lq] = vreg[KF - 1];
        if (lane == 63) bound[wvx] = vreg[KF - 1];
        inc_pipe = __shfl_up(vreg[KF - 1], 1, 64);

        if (FAST) {
            // stream lastv(t-1) out; lvR untouched by this frame's writers
            if (wvx == 15 && t > 0 && lane < (NP >> 2)) {
                int c = lane << 2;
                int bb = c / T, cib = c - bb * T;       // T%4==0: float4 within one beat
                float4 v4 = *(const float4*)&lvR[(bb << 6) + cib];
                *(float4*)&ws_lastv[(size_t)(t - 1) * NP + c] = v4;
            }
        } else {
            int tB = t & (TBATCH - 1);
            if (tB == TBATCH - 1 || t == F - 1) {
                int nbytes = (tB + 1) * NP;
                int t0 = t - tB;
                for (int off = tid * 4; off < nbytes; off += 4096) {
                    uint32_t w = *(const uint32_t*)&argi_s[off];
                    *(uint32_t*)&ws_argi[(size_t)t0 * NP + off] = w;
                }
            }
        }
    }

    // ---- final argmax (first occurrence = smallest s)
    __syncthreads();
    float mv = -INFINITY; int ms = 0x7FFFFFFF;
    #pragma unroll
    for (int kk = 0; kk < KF; kk++) {
        int s = sb + kk;
        bool valid = act_u && (s >= startg);
        float v = vreg[kk];
        if (valid && v > mv) { mv = v; ms = s; }
    }
    #pragma unroll
    for (int d = 1; d < 64; d <<= 1) {
        float ov = __shfl_xor(mv, d, 64);
        int   os = __shfl_xor(ms, d, 64);
        if (ov > mv || (ov == mv && os < ms)) { mv = ov; ms = os; }
    }
    if (lane == 0) { wvs[wvx] = mv; wss[wvx] = ms; }
    __syncthreads();

    if (tid == 0) {
        float bm = -INFINITY; int bs = 0x7FFFFFFF;
        for (int w = 0; w < 16; w++) {
            if (wvs[w] > bm || (wvs[w] == bm && wss[w] < bs)) { bm = wvs[w]; bs = wss[w]; }
        }
        int s = bs;
        int t = F - 1;
        out[F - 1] = (float)s;
        while (t > 0) {
            int b = s / nsb;
            int lo = b * T, hi = b * T + T - 1;
            while (lo < hi) { int mid = (lo + hi + 1) >> 1; if (fsld[mid] <= s) lo = mid; else hi = mid - 1; }
            int p = lo;
            int run = s - fsld[p];
            if (run == 0) {
                int ai;
                if (FAST) {
                    // recompute argmax exactly in reference scan order
                    int jt = p - b * T;
                    int pb = (b + 3) & 3;
                    const float* lrow = &ws_lastv[(size_t)(t - 1) * NP + pb * T];
                    float bmv = -INFINITY; ai = 0;
                    for (int i = 0; i < T; i++) {
                        int idx = (b * T + i) * T + jt;
                        float ltv = isbf ? bf16u_to_f(lt_u[idx]) : lt_f[idx];
                        float sc = lrow[i] + ltv;
                        if (sc > bmv) { bmv = sc; ai = i; }
                    }
                } else {
                    ai = ws_argi[(size_t)t * NP + p];
                }
                s = plds[b * T + ai];
                out[t - 1] = (float)s;
                t--;
            } else {
                int m = (run < t) ? run : t;
                for (int jj = 0; jj < m; jj++) out[t - 1 - jj] = (float)(s - 1 - jj);
                s -= m; t -= m;
            }
        }
        out[F] = bm;   // logp
    }
}

extern "C" void kernel_launch(void* const* d_in, const int* in_sizes, int n_in,
                              void* d_out, int out_size, void* d_ws, size_t ws_size,
                              hipStream_t stream) {
    const int F  = in_sizes[0] / 2;     // frames
    const int NP = in_sizes[2];         // NB*T
    const int T  = NP / NB;             // tempi
    const int S  = in_sizes[4];         // total states

    const bool fast = (ws_size >= (size_t)F * NP * 4) && ((T & 3) == 0) && (NP <= NPMAX);

    if (fast) {
        hipLaunchKernelGGL(dbn_viterbi_kernel<true>, dim3(1), dim3(1024), 0, stream,
                           d_in[0], d_in[1],
                           (const int*)d_in[2], (const int*)d_in[3],
                           (float*)d_out, (float*)d_ws, (uint8_t*)d_ws,
                           T, S, F);
    } else {
        hipLaunchKernelGGL(dbn_viterbi_kernel<false>, dim3(1), dim3(1024), 0, stream,
                           d_in[0], d_in[1],
                           (const int*)d_in[2], (const int*)d_in[3],
                           (float*)d_out, (float*)d_ws, (uint8_t*)d_ws,
                           T, S, F);
    }
}

// Round 9
// 6212.303 us; speedup vs baseline: 1.5160x; 1.0448x over previous
//
#include <hip/hip_runtime.h>
#include <stdint.h>

// DBN downbeat Viterbi, single persistent 1024-thread workgroup, v in REGISTERS.
// v2 (FAST2): zero per-frame vmem. dens precomputed to ws at startup, consumed
// via 64-deep LDS ring (wave-15 HALF-refill, 32 frames per 32 frames — r8 bug
// was refilling 64 and clobbering the live half); lastv history in a 32-slot
// LDS ring, flushed to ws 16 frames at a time (vmcnt drains amortized).
// Banded argmax (data-driven span<=44, cb clamped to row): 3x float4 + 12-cand max tree.
// v1 fallback = round-7 kernel. Output: float32 (path + logp). Bit-exact.

#define NB 4
#define KF 15
#define QW 16
#define NPMAX 256
#define TBATCH 32
#define NEGV -1.0e30f

__device__ __forceinline__ float bf16u_to_f(uint16_t u) {
    union { uint32_t i; float f; } v; v.i = ((uint32_t)u) << 16; return v.f;
}

template<int CTRL>
__device__ __forceinline__ int dpp_i(int x) {
    return __builtin_amdgcn_update_dpp(0, x, CTRL, 0xF, 0xF, true);
}
template<int CTRL>
__device__ __forceinline__ float dpp_f(float x) {
    return __int_as_float(dpp_i<CTRL>(__float_as_int(x)));
}

__device__ __forceinline__ void load_acts(const void* p, int isbf, int t, float& a, float& d) {
    if (isbf) {
        const uint16_t* u = (const uint16_t*)p;
        uint32_t w = *(const uint32_t*)(u + 2 * t);
        a = bf16u_to_f((uint16_t)w); d = bf16u_to_f((uint16_t)(w >> 16));
    } else {
        const float2* f = (const float2*)p;
        float2 v = f[t]; a = v.x; d = v.y;
    }
}

// ============================ v2 kernel ============================
__global__ __launch_bounds__(1024) void dbn_viterbi_v2(
    const void* __restrict__ acts_raw,     // F*2, f32 or bf16 (detected)
    const void* __restrict__ lt_raw,       // NB*T*T, f32 or bf16
    const int*  __restrict__ prev_last,    // NB*T
    const int*  __restrict__ first_states, // NB*T
    float*      __restrict__ out,          // F+1 float32
    float*      __restrict__ ws_lastv,     // F*NP floats
    float*      __restrict__ ws_dens,      // F*4 floats
    int T, int S, int F)
{
    const int tid  = (int)threadIdx.x;
    const int NP   = NB * T;
    const int lane = tid & 63;
    const int wvx  = tid >> 6;

    __shared__ alignas(16) float lring[32 * 256];  // lastv ring [slot][beat<<6|i]
    __shared__ alignas(16) float densr[64 * 4];    // dens ring [slot][d0,d1,d2,-]
    __shared__ float bestv[NPMAX];
    __shared__ float bound[16];
    __shared__ int   fsld[NPMAX];
    __shared__ int   plds[NPMAX];
    __shared__ int   pref[NPMAX + 1];
    __shared__ float wvs[16];
    __shared__ int   wss[16];
    __shared__ int   flag_s, mspan_s;

    // ---- dtype detection on acts (bf16 exponent bytes in [0x20,0x40))
    if (tid == 0) {
        const uint16_t* au = (const uint16_t*)acts_raw;
        int bf = 1;
        for (int i = 0; i < 32; i++) {
            uint16_t e = au[2 * i];
            uint8_t h8 = (uint8_t)(e >> 8);
            if (!(e == 0 || (h8 >= 0x20 && h8 < 0x40))) bf = 0;
        }
        flag_s = bf; mspan_s = 0;
    }
    if (tid < NP) { fsld[tid] = first_states[tid]; plds[tid] = prev_last[tid]; }
    for (int i = tid; i < 32 * 256; i += 1024) lring[i] = NEGV;
    __syncthreads();
    const int isbf = flag_s;
    const int nsb  = S / NB;
    const uint16_t* lt_u = (const uint16_t*)lt_raw;
    const float*    lt_f = (const float*)lt_raw;

    // ---- dens precompute (all frames) into ws_dens
    for (int f = tid; f < F; f += 1024) {
        float ab, ad;
        load_acts(acts_raw, isbf, f, ab, ad);
        float4 r;
        r.x = logf(((1.0f - ab) - ad) / 15.0f);
        r.y = logf(ab);
        r.z = logf(ad);
        r.w = 0.0f;
        *(float4*)&ws_dens[f * 4] = r;
    }
    __threadfence();

    // ---- thread-count prefix over blocks
    if (tid == 0) {
        int acc = 0;
        for (int g = 0; g < NP; g++) {
            int b = g / T, ib = g - b * T;
            int end = (ib + 1 < T) ? fsld[g + 1] : (b + 1) * nsb;
            int L = end - fsld[g];
            pref[g] = acc; acc += (L + KF - 1) / KF;
        }
        pref[NP] = acc;
    }
    __syncthreads();
    const int NT = pref[NP];

    // ---- update-side assignment (end-aligned within block)
    const bool act_u = (tid < NT);
    int g_own = 0, startg = 0, Lg = 1, sb = 0, lq = 0;
    bool is_last = false, pv2 = false;
    if (act_u) {
        int lo = 0, hi = NP - 1;
        while (lo < hi) { int mid = (lo + hi + 1) >> 1; if (pref[mid] <= tid) lo = mid; else hi = mid - 1; }
        g_own = lo;
        int j = tid - pref[lo];
        int b = g_own / T, ib = g_own - b * T;
        startg = fsld[g_own];
        int end = (ib + 1 < T) ? fsld[g_own + 1] : (b + 1) * nsb;
        Lg = end - startg;
        int n = (Lg + KF - 1) / KF;
        sb = startg + Lg - KF * (n - j);
        is_last = (j == n - 1);
        lq = (b << 6) + ib;
        pv2 = (b == 0);
    }
    bool hb[KF], hq[KF];
    #pragma unroll
    for (int kk = 0; kk < KF; kk++) {
        int i = sb + kk - startg;
        hq[kk] = act_u && (i <= 0);
        hb[kk] = act_u && (16 * i < Lg);
    }

    // ---- argmax-side setup: find band, fill ltreg
    const int g_a = tid >> 2, k4 = tid & 3;
    const bool act_g = (g_a < NP);
    int rowbase = 0, lo_b = 0;
    int b_a = 0, j_a = 0;
    if (act_g) {
        b_a = g_a / T; j_a = g_a - b_a * T;
        rowbase = ((b_a + 3) & 3) << 6;
        int lo = T, hi = 0;
        for (int i = 0; i < T; i++) {
            int idx = (b_a * T + i) * T + j_a;
            float v = isbf ? bf16u_to_f(lt_u[idx]) : lt_f[idx];
            if (v > -1e29f) { if (i < lo) lo = i; hi = i; }
        }
        lo_b = lo;
        if (k4 == 0) atomicMax(&mspan_s, hi - lo + 1);
    }
    __syncthreads();
    const bool banded = (mspan_s <= 44);
    float ltreg[QW];
    #pragma unroll
    for (int u = 0; u < QW; u++) ltreg[u] = NEGV;
    int cb = 0;
    if (act_g) {
        if (banded) {
            cb = (lo_b & ~3) + 12 * k4;
            if (cb > 52) cb = 52;          // stay inside the 64-float row; dups harmless (max-only)
        } else {
            cb = 16 * k4;
        }
        const int nu = banded ? 12 : 16;
        for (int u = 0; u < nu; u++) {
            int i = cb + u;
            if (i < T) {
                int idx = (b_a * T + i) * T + j_a;
                ltreg[u] = isbf ? bf16u_to_f(lt_u[idx]) : lt_f[idx];
            }
        }
    }

    // ---- init state
    const float vinit = -logf((float)S);
    float vreg[KF];
    #pragma unroll
    for (int kk = 0; kk < KF; kk++) vreg[kk] = vinit;
    if (act_u && is_last) lring[(31 << 8) + lq] = vinit;   // t=0 reads slot 31
    if (lane == 63) bound[wvx] = vinit;
    float inc_pipe = vinit;
    // preload dens ring frames 0..63
    if (tid < 64 && tid < F) {
        float4 r = *(const float4*)&ws_dens[tid * 4];
        *(float4*)&densr[tid * 4] = r;
    }

    const int WQ = NP >> 2;        // float4s per lastv row
    const int TQ = T >> 2;         // float4s per beat

    // ---- main loop, 2 barriers/frame, no per-frame vmem
    for (int t = 0; t < F; t++) {
        __syncthreads();   // A: lring[(t-1)&31] + bound visible
        const float* lvR = &lring[((t + 31) & 31) << 8];
        float inc_use = inc_pipe;
        if (lane == 0) inc_use = bound[(wvx + 15) & 15];

        if (wvx == 15) {
            if ((t & 31) == 0 && t >= 32 && lane < 32) {   // HALF refill: frames t+32..t+63
                int fr = t + 32 + lane;                    // slots disjoint from live half
                if (fr < F) {
                    float4 r = *(const float4*)&ws_dens[fr * 4];
                    *(float4*)&densr[(fr & 63) * 4] = r;
                }
            }
            if ((t & 15) == 0 && t > 0 && lane < WQ) {     // lastv batch flush
                int c = lane;
                int beat = c / TQ;
                int srcoff = 4 * c + 4 * beat;
                int t0 = t - 16;
                for (int r2 = 0; r2 < 16; r2++) {
                    int row = t0 + r2;
                    float4 v4 = *(const float4*)&lring[((row & 31) << 8) + srcoff];
                    *(float4*)&ws_lastv[(size_t)row * NP + 4 * c] = v4;
                }
            }
        } else if (act_g) {
            const float* rowp = lvR + rowbase + cb;
            if (banded) {
                float4 l0 = *(const float4*)(rowp + 0);
                float4 l1 = *(const float4*)(rowp + 4);
                float4 l2 = *(const float4*)(rowp + 8);
                float m0 = fmaxf(fmaxf(l0.x + ltreg[0], l0.y + ltreg[1]),
                                 fmaxf(l0.z + ltreg[2], l0.w + ltreg[3]));
                float m1 = fmaxf(fmaxf(l1.x + ltreg[4], l1.y + ltreg[5]),
                                 fmaxf(l1.z + ltreg[6], l1.w + ltreg[7]));
                float m2 = fmaxf(fmaxf(l2.x + ltreg[8], l2.y + ltreg[9]),
                                 fmaxf(l2.z + ltreg[10], l2.w + ltreg[11]));
                float mv = fmaxf(fmaxf(m0, m1), m2);
                mv = fmaxf(mv, dpp_f<0xB1>(mv));
                mv = fmaxf(mv, dpp_f<0x4E>(mv));
                if (k4 == 0) bestv[g_a] = mv;
            } else {
                float4 l0 = *(const float4*)(rowp + 0);
                float4 l1 = *(const float4*)(rowp + 4);
                float4 l2 = *(const float4*)(rowp + 8);
                float4 l3 = *(const float4*)(rowp + 12);
                float m0 = fmaxf(fmaxf(l0.x + ltreg[0], l0.y + ltreg[1]),
                                 fmaxf(l0.z + ltreg[2], l0.w + ltreg[3]));
                float m1 = fmaxf(fmaxf(l1.x + ltreg[4], l1.y + ltreg[5]),
                                 fmaxf(l1.z + ltreg[6], l1.w + ltreg[7]));
                float m2 = fmaxf(fmaxf(l2.x + ltreg[8], l2.y + ltreg[9]),
                                 fmaxf(l2.z + ltreg[10], l2.w + ltreg[11]));
                float m3 = fmaxf(fmaxf(l3.x + ltreg[12], l3.y + ltreg[13]),
                                 fmaxf(l3.z + ltreg[14], l3.w + ltreg[15]));
                float mv = fmaxf(fmaxf(m0, m1), fmaxf(m2, m3));
                mv = fmaxf(mv, dpp_f<0xB1>(mv));
                mv = fmaxf(mv, dpp_f<0x4E>(mv));
                if (k4 == 0) bestv[g_a] = mv;
            }
        }

        __syncthreads();   // B: bestv visible; lvR reads done
        int doff = (t & 63) << 2;
        float d0  = densr[doff];
        float dpv = densr[doff + (pv2 ? 2 : 1)];
        float bq  = bestv[g_own];
        #pragma unroll
        for (int kk = KF - 1; kk >= 0; kk--) {
            float prev = (kk == 0) ? inc_use : vreg[kk - 1];
            prev = hq[kk] ? bq : prev;
            float add = hb[kk] ? dpv : d0;
            vreg[kk] = prev + add;               // bit-exact vs reference
        }
        if (act_u && is_last) lring[((t & 31) << 8) + lq] = vreg[KF - 1];
        if (lane == 63) bound[wvx] = vreg[KF - 1];
        inc_pipe = __shfl_up(vreg[KF - 1], 1, 64);
    }

    // ---- flush remaining lastv rows [lastf, F-2]
    __syncthreads();
    if (wvx == 15 && lane < WQ) {
        int lastf = (F - 1) & ~15;
        int c = lane;
        int beat = c / TQ;
        int srcoff = 4 * c + 4 * beat;
        for (int row = lastf; row <= F - 2; row++) {
            float4 v4 = *(const float4*)&lring[((row & 31) << 8) + srcoff];
            *(float4*)&ws_lastv[(size_t)row * NP + 4 * c] = v4;
        }
        __threadfence();
    }

    // ---- final argmax (first occurrence = smallest s)
    float mv = -INFINITY; int ms = 0x7FFFFFFF;
    #pragma unroll
    for (int kk = 0; kk < KF; kk++) {
        int s = sb + kk;
        bool valid = act_u && (s >= startg);
        float v = vreg[kk];
        if (valid && v > mv) { mv = v; ms = s; }
    }
    #pragma unroll
    for (int d = 1; d < 64; d <<= 1) {
        float ov = __shfl_xor(mv, d, 64);
        int   os = __shfl_xor(ms, d, 64);
        if (ov > mv || (ov == mv && os < ms)) { mv = ov; ms = os; }
    }
    if (lane == 0) { wvs[wvx] = mv; wss[wvx] = ms; }
    __syncthreads();

    if (tid == 0) {
        float bm = -INFINITY; int bs = 0x7FFFFFFF;
        for (int w = 0; w < 16; w++) {
            if (wvs[w] > bm || (wvs[w] == bm && wss[w] < bs)) { bm = wvs[w]; bs = wss[w]; }
        }
        int s = bs;
        int t = F - 1;
        out[F - 1] = (float)s;
        while (t > 0) {
            int b = s / nsb;
            int lo = b * T, hi = b * T + T - 1;
            while (lo < hi) { int mid = (lo + hi + 1) >> 1; if (fsld[mid] <= s) lo = mid; else hi = mid - 1; }
            int p = lo;
            int run = s - fsld[p];
            if (run == 0) {
                // recompute argmax exactly in reference scan order
                int jt = p - b * T;
                int pb = (b + 3) & 3;
                const float* lrow = &ws_lastv[(size_t)(t - 1) * NP + pb * T];
                float bmv = -INFINITY; int ai = 0;
                for (int i = 0; i < T; i++) {
                    int idx = (b * T + i) * T + jt;
                    float ltv = isbf ? bf16u_to_f(lt_u[idx]) : lt_f[idx];
                    float sc = lrow[i] + ltv;
                    if (sc > bmv) { bmv = sc; ai = i; }
                }
                s = plds[b * T + ai];
                out[t - 1] = (float)s;
                t--;
            } else {
                int m = (run < t) ? run : t;
                for (int jj = 0; jj < m; jj++) out[t - 1 - jj] = (float)(s - 1 - jj);
                s -= m; t -= m;
            }
        }
        out[F] = bm;   // logp
    }
}

// ============================ v1 kernel (round-7, fallback) ============================
template<bool FAST>
__global__ __launch_bounds__(1024) void dbn_viterbi_kernel(
    const void* __restrict__ acts_raw, const void* __restrict__ lt_raw,
    const int* __restrict__ prev_last, const int* __restrict__ first_states,
    float* __restrict__ out, float* __restrict__ ws_lastv, uint8_t* __restrict__ ws_argi,
    int T, int S, int F)
{
    const int tid  = (int)threadIdx.x;
    const int NP   = NB * T;
    const int lane = tid & 63;
    const int wvx  = tid >> 6;

    __shared__ alignas(16) float lastv2[2 * NB * 64];
    __shared__ float bestv[NPMAX];
    __shared__ float bound[16];
    __shared__ int   fsld[NPMAX];
    __shared__ int   plds[NPMAX];
    __shared__ int   pref[NPMAX + 1];
    __shared__ float dens_s[4];
    __shared__ float wvs[16];
    __shared__ int   wss[16];
    __shared__ int   flag_s;
    __shared__ uint8_t argi_s[TBATCH * 240 + 16];

    if (tid == 0) {
        const uint16_t* au = (const uint16_t*)acts_raw;
        int bf = 1;
        for (int i = 0; i < 32; i++) {
            uint16_t e = au[2 * i];
            uint8_t h8 = (uint8_t)(e >> 8);
            if (!(e == 0 || (h8 >= 0x20 && h8 < 0x40))) bf = 0;
        }
        flag_s = bf;
    }
    if (tid < NP)          { fsld[tid] = first_states[tid]; plds[tid] = prev_last[tid]; }
    if (tid < 2 * NB * 64) lastv2[tid] = NEGV;
    __syncthreads();
    const int isbf = flag_s;
    const int nsb  = S / NB;
    const uint16_t* lt_u = (const uint16_t*)lt_raw;
    const float*    lt_f = (const float*)lt_raw;

    if (tid == 0) {
        int acc = 0;
        for (int g = 0; g < NP; g++) {
            int b = g / T, ib = g - b * T;
            int end = (ib + 1 < T) ? fsld[g + 1] : (b + 1) * nsb;
            int L = end - fsld[g];
            pref[g] = acc; acc += (L + KF - 1) / KF;
        }
        pref[NP] = acc;
    }
    __syncthreads();
    const int NT = pref[NP];

    const bool act_u = (tid < NT);
    int g_own = 0, startg = 0, Lg = 1, sb = 0, lq = 0;
    bool is_last = false, pv2 = false;
    if (act_u) {
        int lo = 0, hi = NP - 1;
        while (lo < hi) { int mid = (lo + hi + 1) >> 1; if (pref[mid] <= tid) lo = mid; else hi = mid - 1; }
        g_own = lo;
        int j = tid - pref[lo];
        int b = g_own / T, ib = g_own - b * T;
        startg = fsld[g_own];
        int end = (ib + 1 < T) ? fsld[g_own + 1] : (b + 1) * nsb;
        Lg = end - startg;
        int n = (Lg + KF - 1) / KF;
        sb = startg + Lg - KF * (n - j);
        is_last = (j == n - 1);
        lq = (b << 6) + ib;
        pv2 = (b == 0);
    }
    bool hb[KF], hq[KF];
    #pragma unroll
    for (int kk = 0; kk < KF; kk++) {
        int i = sb + kk - startg;
        hq[kk] = act_u && (i <= 0);
        hb[kk] = act_u && (16 * i < Lg);
    }

    const int g_a = tid >> 2, k4 = tid & 3;
    const bool act_g = (g_a < NP);
    float ltreg[QW];
    #pragma unroll
    for (int u = 0; u < QW; u++) ltreg[u] = NEGV;
    int rowbase = 0;
    if (act_g) {
        int b = g_a / T, j = g_a - (g_a / T) * T;
        rowbase = ((b + 3) & 3) << 6;
        #pragma unroll
        for (int u = 0; u < QW; u++) {
            int i = k4 * QW + u;
            if (i < T) {
                int idx = (b * T + i) * T + j;
                ltreg[u] = isbf ? bf16u_to_f(lt_u[idx]) : lt_f[idx];
            }
        }
    }

    const float vinit = -logf((float)S);
    float vreg[KF];
    #pragma unroll
    for (int kk = 0; kk < KF; kk++) vreg[kk] = vinit;
    if (act_u && is_last) lastv2[256 + lq] = vinit;
    if (lane == 63) bound[wvx] = vinit;
    float inc_pipe = vinit;
    float ab_c = 0.0f, ad_c = 0.0f;
    if (wvx == 15 && lane >= 60 && lane < 63) load_acts(acts_raw, isbf, 0, ab_c, ad_c);

    for (int t = 0; t < F; t++) {
        __syncthreads();
        const float* lvR = lastv2 + (((t & 1) ^ 1) << 8);
        float inc_use = inc_pipe;
        if (lane == 0) inc_use = bound[(wvx + 15) & 15];

        if (wvx == 15) {
            if (lane >= 60 && lane < 63) {
                int c3 = lane - 60;
                float dv = (c3 == 0) ? logf(((1.0f - ab_c) - ad_c) / 15.0f)
                         : (c3 == 1) ? logf(ab_c) : logf(ad_c);
                dens_s[c3] = dv;
                if (t + 1 < F) load_acts(acts_raw, isbf, t + 1, ab_c, ad_c);
            }
        } else if (act_g) {
            const float* rowp = &lvR[rowbase + k4 * QW];
            float4 l0 = *(const float4*)(rowp + 0);
            float4 l1 = *(const float4*)(rowp + 4);
            float4 l2 = *(const float4*)(rowp + 8);
            float4 l3 = *(const float4*)(rowp + 12);
            if (FAST) {
                float m0 = fmaxf(fmaxf(l0.x + ltreg[0],  l0.y + ltreg[1]),
                                 fmaxf(l0.z + ltreg[2],  l0.w + ltreg[3]));
                float m1 = fmaxf(fmaxf(l1.x + ltreg[4],  l1.y + ltreg[5]),
                                 fmaxf(l1.z + ltreg[6],  l1.w + ltreg[7]));
                float m2 = fmaxf(fmaxf(l2.x + ltreg[8],  l2.y + ltreg[9]),
                                 fmaxf(l2.z + ltreg[10], l2.w + ltreg[11]));
                float m3 = fmaxf(fmaxf(l3.x + ltreg[12], l3.y + ltreg[13]),
                                 fmaxf(l3.z + ltreg[14], l3.w + ltreg[15]));
                float mv = fmaxf(fmaxf(m0, m1), fmaxf(m2, m3));
                mv = fmaxf(mv, dpp_f<0xB1>(mv));
                mv = fmaxf(mv, dpp_f<0x4E>(mv));
                if (k4 == 0) bestv[g_a] = mv;
            } else {
                float cand[QW] = { l0.x, l0.y, l0.z, l0.w, l1.x, l1.y, l1.z, l1.w,
                                   l2.x, l2.y, l2.z, l2.w, l3.x, l3.y, l3.z, l3.w };
                float mv = -INFINITY; int ai = 0;
                #pragma unroll
                for (int u = 0; u < QW; u++) {
                    float sc = cand[u] + ltreg[u];
                    if (sc > mv) { mv = sc; ai = k4 * QW + u; }
                }
                float ov = dpp_f<0xB1>(mv); int oa = dpp_i<0xB1>(ai);
                if (ov > mv || (ov == mv && oa < ai)) { mv = ov; ai = oa; }
                ov = dpp_f<0x4E>(mv); oa = dpp_i<0x4E>(ai);
                if (ov > mv || (ov == mv && oa < ai)) { mv = ov; ai = oa; }
                if (k4 == 0) {
                    bestv[g_a] = mv;
                    argi_s[(t & (TBATCH - 1)) * NP + g_a] = (uint8_t)ai;
                }
            }
        }

        __syncthreads();
        float d0  = dens_s[0];
        float dpv = pv2 ? dens_s[2] : dens_s[1];
        float bq  = bestv[g_own];
        #pragma unroll
        for (int kk = KF - 1; kk >= 0; kk--) {
            float prev = (kk == 0) ? inc_use : vreg[kk - 1];
            prev = hq[kk] ? bq : prev;
            float add = hb[kk] ? dpv : d0;
            vreg[kk] = prev + add;
        }
        float* lvW = lastv2 + ((t & 1) << 8);
        if (act_u && is_last) lvW[lq] = vreg[KF - 1];
        if (lane == 63) bound[wvx] = vreg[KF - 1];
        inc_pipe = __shfl_up(vreg[KF - 1], 1, 64);

        if (FAST) {
            if (wvx == 15 && t > 0 && lane < (NP >> 2)) {
                int c = lane << 2;
                int bb = c / T, cib = c - bb * T;
                float4 v4 = *(const float4*)&lvR[(bb << 6) + cib];
                *(float4*)&ws_lastv[(size_t)(t - 1) * NP + c] = v4;
            }
        } else {
            int tB = t & (TBATCH - 1);
            if (tB == TBATCH - 1 || t == F - 1) {
                int nbytes = (tB + 1) * NP;
                int t0 = t - tB;
                for (int off = tid * 4; off < nbytes; off += 4096) {
                    uint32_t w = *(const uint32_t*)&argi_s[off];
                    *(uint32_t*)&ws_argi[(size_t)t0 * NP + off] = w;
                }
            }
        }
    }

    __syncthreads();
    float mv = -INFINITY; int ms = 0x7FFFFFFF;
    #pragma unroll
    for (int kk = 0; kk < KF; kk++) {
        int s = sb + kk;
        bool valid = act_u && (s >= startg);
        float v = vreg[kk];
        if (valid && v > mv) { mv = v; ms = s; }
    }
    #pragma unroll
    for (int d = 1; d < 64; d <<= 1) {
        float ov = __shfl_xor(mv, d, 64);
        int   os = __shfl_xor(ms, d, 64);
        if (ov > mv || (ov == mv && os < ms)) { mv = ov; ms = os; }
    }
    if (lane == 0) { wvs[wvx] = mv; wss[wvx] = ms; }
    __syncthreads();

    if (tid == 0) {
        float bm = -INFINITY; int bs = 0x7FFFFFFF;
        for (int w = 0; w < 16; w++) {
            if (wvs[w] > bm || (wvs[w] == bm && wss[w] < bs)) { bm = wvs[w]; bs = wss[w]; }
        }
        int s = bs;
        int t = F - 1;
        out[F - 1] = (float)s;
        while (t > 0) {
            int b = s / nsb;
            int lo = b * T, hi = b * T + T - 1;
            while (lo < hi) { int mid = (lo + hi + 1) >> 1; if (fsld[mid] <= s) lo = mid; else hi = mid - 1; }
            int p = lo;
            int run = s - fsld[p];
            if (run == 0) {
                int ai;
                if (FAST) {
                    int jt = p - b * T;
                    int pb = (b + 3) & 3;
                    const float* lrow = &ws_lastv[(size_t)(t - 1) * NP + pb * T];
                    float bmv = -INFINITY; ai = 0;
                    for (int i = 0; i < T; i++) {
                        int idx = (b * T + i) * T + jt;
                        float ltv = isbf ? bf16u_to_f(lt_u[idx]) : lt_f[idx];
                        float sc = lrow[i] + ltv;
                        if (sc > bmv) { bmv = sc; ai = i; }
                    }
                } else {
                    ai = ws_argi[(size_t)t * NP + p];
                }
                s = plds[b * T + ai];
                out[t - 1] = (float)s;
                t--;
            } else {
                int m = (run < t) ? run : t;
                for (int jj = 0; jj < m; jj++) out[t - 1 - jj] = (float)(s - 1 - jj);
                s -= m; t -= m;
            }
        }
        out[F] = bm;
    }
}

extern "C" void kernel_launch(void* const* d_in, const int* in_sizes, int n_in,
                              void* d_out, int out_size, void* d_ws, size_t ws_size,
                              hipStream_t stream) {
    const int F  = in_sizes[0] / 2;     // frames
    const int NP = in_sizes[2];         // NB*T
    const int T  = NP / NB;             // tempi
    const int S  = in_sizes[4];         // total states

    const size_t need2 = ((size_t)F * NP + 4 * (size_t)F) * 4;
    const bool okgeom = ((T & 3) == 0) && (NP <= NPMAX) && (T <= 64) && (F >= 2);
    const bool fast2  = okgeom && (ws_size >= need2);
    const bool fast1  = okgeom && (ws_size >= (size_t)F * NP * 4);

    if (fast2) {
        float* ws_lv = (float*)d_ws;
        float* ws_de = ws_lv + (size_t)F * NP;
        hipLaunchKernelGGL(dbn_viterbi_v2, dim3(1), dim3(1024), 0, stream,
                           d_in[0], d_in[1],
                           (const int*)d_in[2], (const int*)d_in[3],
                           (float*)d_out, ws_lv, ws_de, T, S, F);
    } else if (fast1) {
        hipLaunchKernelGGL(dbn_viterbi_kernel<true>, dim3(1), dim3(1024), 0, stream,
                           d_in[0], d_in[1],
                           (const int*)d_in[2], (const int*)d_in[3],
                           (float*)d_out, (float*)d_ws, (uint8_t*)d_ws, T, S, F);
    } else {
        hipLaunchKernelGGL(dbn_viterbi_kernel<false>, dim3(1), dim3(1024), 0, stream,
                           d_in[0], d_in[1],
                           (const int*)d_in[2], (const int*)d_in[3],
                           (float*)d_out, (float*)d_ws, (uint8_t*)d_ws, T, S, F);
    }
}